// Round 5
// baseline (175.752 us; speedup 1.0000x reference)
//
#include <hip/hip_runtime.h>

// B=8, Cin=Cout=32, H=W=256, K=5. Adaptive bins: start (k*256)/5, all length 52.
// filt = pooled feat / 52^2.
// out[b,o,y,x] = sum_{kh,kw} filt[b,o,kh,kw] * feat[b,o,y-2+kh,x-2+kw]  (zero pad 2)

#define CIN 32
#define COUT 32
#define HW 256
#define PLANE (HW * HW)
#define BATCH 8
#define KF 5
#define BIN 52

// ---------------- K1: 1x1 conv + fused pool. Thread = 4 px (float4) x 8 o. ----------------
// Block = (b, 4-row group, o-group of 8). x re-read x4 across o-groups -> L3-served.
// acc 32 VGPR + xv 16 VGPR keeps total ~75 -> good occupancy AND 1KB/instr IO.
#define PROW 260   // pool LDS row stride (floats): 16B aligned, bank-spreads reduce jobs
__global__ __launch_bounds__(256) void conv1x1_pool_kernel(const float* __restrict__ x,
                                                           const float* __restrict__ Wm,
                                                           const float* __restrict__ bias,
                                                           float* __restrict__ feat,
                                                           float* __restrict__ filt_raw) {
    int b   = blockIdx.x >> 8;
    int rem = blockIdx.x & 255;
    int rg  = rem >> 2;            // 0..63: rows 4rg..4rg+3
    int og  = rem & 3;             // 0..3:  o's 8og..8og+7
    int r0  = rg * 4, o0 = og * 8;
    int t   = threadIdx.x;
    int rp  = t >> 6;              // 0..3 (one full row per wave)
    int c0  = (t & 63) * 4;
    int row = r0 + rp;

    const float* xb = x + (size_t)b * CIN * PLANE + row * HW + c0;

    float4 acc[8];
#pragma unroll
    for (int oo = 0; oo < 8; ++oo) {
        float bv = bias[o0 + oo];
        acc[oo].x = bv; acc[oo].y = bv; acc[oo].z = bv; acc[oo].w = bv;
    }

#pragma unroll
    for (int ig = 0; ig < 8; ++ig) {       // i-chunks of 4
        float4 xv[4];
#pragma unroll
        for (int j = 0; j < 4; ++j) xv[j] = *(const float4*)(xb + (size_t)(ig * 4 + j) * PLANE);
#pragma unroll
        for (int oo = 0; oo < 8; ++oo) {
#pragma unroll
            for (int j = 0; j < 4; ++j) {
                float wv = Wm[(o0 + oo) * CIN + ig * 4 + j];   // uniform -> s_load
                acc[oo].x += wv * xv[j].x; acc[oo].y += wv * xv[j].y;
                acc[oo].z += wv * xv[j].z; acc[oo].w += wv * xv[j].w;
            }
        }
    }

    float* fb = feat + ((size_t)b * COUT + o0) * PLANE + row * HW + c0;
#pragma unroll
    for (int oo = 0; oo < 8; ++oo) *(float4*)(fb + (size_t)oo * PLANE) = acc[oo];

    // ---- pool: rows r0..r0+3, o0..o0+7 contribution to filt ----
    __shared__ __align__(16) float lds[8 * 4 * PROW];   // 33.3 KB
#pragma unroll
    for (int oo = 0; oo < 8; ++oo)
        *(float4*)(&lds[(oo * 4 + rp) * PROW + c0]) = acc[oo];
    __syncthreads();

    if (t < 160) {                 // job = (oo, rr, l)
        int oo = t / 20;
        int rr = (t / 5) % 4;
        int l  = t % 5;
        int sl = (l * HW) / KF;
        const float* lp = &lds[(oo * 4 + rr) * PROW + sl];
        float s = 0.f;
        for (int w = 0; w < BIN; ++w) s += lp[w];
        int row2 = r0 + rr;
        float* dst = filt_raw + (size_t)(b * COUT + o0 + oo) * 25 + l;
#pragma unroll
        for (int k = 0; k < KF; ++k) {
            int sk = (k * HW) / KF;
            if (row2 >= sk && row2 < sk + BIN) atomicAdd(dst + k * KF, s);
        }
    }
}

// ---------------- K3: depthwise 5x5. 32-row strips; thread = 4 cols x 8 rows ----------
#define LROW 264
__global__ __launch_bounds__(256) void dwconv_kernel(const float* __restrict__ feat,
                                                     const float* __restrict__ filt_raw,
                                                     float* __restrict__ out) {
    int bo    = blockIdx.y;            // 0..255
    int strip = blockIdx.x;            // 0..7
    int gy0   = strip * 32;
    int t     = threadIdx.x;

    __shared__ __align__(16) float s[36 * LROW];    // 38 KB -> 4 blocks/CU
    __shared__ float sfilt[25];
    if (t < 25) sfilt[t] = filt_raw[bo * 25 + t] * (1.0f / (52.0f * 52.0f));
    for (int idx = t; idx < 288; idx += 256) {      // zero pads: 36 rows x 8 cols
        int lr = idx >> 3, e = idx & 7;
        int ci = (e < 4) ? e : (256 + e);
        s[lr * LROW + ci] = 0.f;
    }

    const float* fb = feat + (size_t)bo * PLANE;
#pragma unroll
    for (int j = 0; j < 9; ++j) {      // 36 rows x 64 float4 = 2304 / 256 threads
        int idx = t + 256 * j;
        int lr  = idx >> 6;
        int cx  = (idx & 63) * 4;
        int gy  = gy0 - 2 + lr;
        float4 v = {0.f, 0.f, 0.f, 0.f};
        if ((unsigned)gy < (unsigned)HW) v = *(const float4*)(fb + gy * HW + cx);
        *(float4*)(&s[lr * LROW + 4 + cx]) = v;
    }
    __syncthreads();

    float fw[25];
#pragma unroll
    for (int j = 0; j < 25; ++j) fw[j] = sfilt[j];

    int cq  = t & 63;                  // cols 4cq..4cq+3
    int rq  = t >> 6;                  // 0..3 -> rows 8rq..8rq+7 (local)
    int lr0 = rq * 8;
    int ci0 = 4 * cq + 2;              // window idx base (cols 4cq-2..4cq+5)

    float w[5][8];
#pragma unroll
    for (int r = 0; r < 4; ++r) {
        const float* rp = &s[(lr0 + r) * LROW + ci0];
#pragma unroll
        for (int j = 0; j < 4; ++j) {
            float2 v = *(const float2*)(rp + 2 * j);
            w[r][2 * j] = v.x; w[r][2 * j + 1] = v.y;
        }
    }

    float* ob = out + (size_t)bo * PLANE + (size_t)(gy0 + 8 * rq) * HW + 4 * cq;
#pragma unroll
    for (int r = 0; r < 8; ++r) {
        const float* rp = &s[(lr0 + r + 4) * LROW + ci0];
#pragma unroll
        for (int j = 0; j < 4; ++j) {
            float2 v = *(const float2*)(rp + 2 * j);
            w[4][2 * j] = v.x; w[4][2 * j + 1] = v.y;
        }

        float4 a = {0.f, 0.f, 0.f, 0.f};
#pragma unroll
        for (int kh = 0; kh < 5; ++kh) {
#pragma unroll
            for (int j = 0; j < 5; ++j) {
                float wv = fw[kh * 5 + j];
                a.x += wv * w[kh][j];
                a.y += wv * w[kh][j + 1];
                a.z += wv * w[kh][j + 2];
                a.w += wv * w[kh][j + 3];
            }
        }
        *(float4*)(ob + r * HW) = a;

#pragma unroll
        for (int kh = 0; kh < 4; ++kh)
#pragma unroll
            for (int j = 0; j < 8; ++j) w[kh][j] = w[kh + 1][j];
    }
}

extern "C" void kernel_launch(void* const* d_in, const int* in_sizes, int n_in,
                              void* d_out, int out_size, void* d_ws, size_t ws_size,
                              hipStream_t stream) {
    const float* x      = (const float*)d_in[0];
    const float* conv_w = (const float*)d_in[1];
    const float* conv_b = (const float*)d_in[2];
    float* out = (float*)d_out;

    float* feat = (float*)d_ws;                           // 64 MiB
    float* filt = feat + (size_t)BATCH * COUT * PLANE;    // 6400 floats (raw sums)

    hipMemsetAsync(filt, 0, BATCH * COUT * 25 * sizeof(float), stream);
    conv1x1_pool_kernel<<<dim3(BATCH * 256), dim3(256), 0, stream>>>(x, conv_w, conv_b, feat, filt);
    dwconv_kernel<<<dim3(8, BATCH * COUT), dim3(256), 0, stream>>>(feat, filt, out);
}